// Round 2
// baseline (429.798 us; speedup 1.0000x reference)
//
#include <hip/hip_runtime.h>

// GraphConvolution: out = segment_sum(edge_val * x[edge_col], edge_row) + x_0 + bias
// (Cayley transform in the reference is exactly identity => support == x.)
//
// Strategy: device-built CSR (histogram -> scan -> counting-sort scatter),
// then gather-side SpMM, one wave per row, output written exactly once.
// Kills the 64M device-scope atomics of the scatter formulation.

#define DFEAT 64
#define SCAN_THREADS 1024

// ---------- fallback path (atomic scatter) ----------
__global__ void init_out_kernel(const float* __restrict__ x0,
                                const float* __restrict__ bias,
                                float* __restrict__ out, int n4) {
    int i = blockIdx.x * blockDim.x + threadIdx.x;
    if (i < n4) {
        float4 v = ((const float4*)x0)[i];
        int d = (i * 4) & (DFEAT - 1);
        v.x += bias[d + 0]; v.y += bias[d + 1];
        v.z += bias[d + 2]; v.w += bias[d + 3];
        ((float4*)out)[i] = v;
    }
}

__global__ void edge_scatter_kernel(const float* __restrict__ x,
                                    const float* __restrict__ edge_val,
                                    const int* __restrict__ edge_row,
                                    const int* __restrict__ edge_col,
                                    float* __restrict__ out, int E) {
    int tid = blockIdx.x * blockDim.x + threadIdx.x;
    int wave = tid >> 6, lane = tid & 63;
    int nwaves = (gridDim.x * blockDim.x) >> 6;
    for (int e = wave; e < E; e += nwaves) {
        int row = edge_row[e];
        int col = edge_col[e];
        float val = edge_val[e];
        atomicAdd(&out[row * DFEAT + lane], val * x[col * DFEAT + lane]);
    }
}

// ---------- CSR path ----------
__global__ void zero_counts_kernel(int* __restrict__ counts, int n) {
    int i = blockIdx.x * blockDim.x + threadIdx.x;
    if (i < n) counts[i] = 0;
}

__global__ void hist_kernel(const int* __restrict__ edge_row,
                            int* __restrict__ counts, int E) {
    int i = blockIdx.x * blockDim.x + threadIdx.x;
    int stride = gridDim.x * blockDim.x;
    for (int e = i; e < E; e += stride)
        atomicAdd(&counts[edge_row[e]], 1);
}

// Single-block exclusive scan of counts[0..n) -> row_start[0..n], cursor copy.
__global__ void scan_kernel(const int* __restrict__ counts,
                            int* __restrict__ row_start,
                            int* __restrict__ cursor, int n) {
    __shared__ int partial[SCAN_THREADS];
    int t = threadIdx.x;
    int per = (n + SCAN_THREADS - 1) / SCAN_THREADS;
    int base = t * per;
    int s = 0;
    for (int i = 0; i < per; i++) {
        int idx = base + i;
        if (idx < n) s += counts[idx];
    }
    partial[t] = s;
    __syncthreads();
    // Hillis-Steele inclusive scan in LDS
    for (int off = 1; off < SCAN_THREADS; off <<= 1) {
        int v = (t >= off) ? partial[t - off] : 0;
        __syncthreads();
        partial[t] += v;
        __syncthreads();
    }
    int run = (t == 0) ? 0 : partial[t - 1];
    for (int i = 0; i < per; i++) {
        int idx = base + i;
        if (idx < n) {
            int c = counts[idx];
            row_start[idx] = run;
            cursor[idx] = run;
            run += c;
        }
    }
    if (t == SCAN_THREADS - 1) row_start[n] = run;
}

__global__ void scatter_sort_kernel(const int* __restrict__ edge_row,
                                    const int* __restrict__ edge_col,
                                    const float* __restrict__ edge_val,
                                    int* __restrict__ cursor,
                                    int* __restrict__ cols_sorted,
                                    float* __restrict__ vals_sorted, int E) {
    int i = blockIdx.x * blockDim.x + threadIdx.x;
    int stride = gridDim.x * blockDim.x;
    for (int e = i; e < E; e += stride) {
        int r = edge_row[e];
        int pos = atomicAdd(&cursor[r], 1);
        cols_sorted[pos] = edge_col[e];
        vals_sorted[pos] = edge_val[e];
    }
}

// One 64-lane wave per row; lane d owns feature d. No atomics.
__global__ void spmm_kernel(const float* __restrict__ x,
                            const float* __restrict__ x0,
                            const float* __restrict__ bias,
                            const int* __restrict__ row_start,
                            const int* __restrict__ cols_sorted,
                            const float* __restrict__ vals_sorted,
                            float* __restrict__ out, int n) {
    int wid = (blockIdx.x * blockDim.x + threadIdx.x) >> 6;
    int lane = threadIdx.x & 63;
    if (wid >= n) return;
    int start = row_start[wid];
    int end   = row_start[wid + 1];
    float acc = 0.f;
    for (int s = start; s < end; s += 64) {
        int m = end - s;
        if (m > 64) m = 64;
        int c = 0; float v = 0.f;
        if (lane < m) { c = cols_sorted[s + lane]; v = vals_sorted[s + lane]; }
        for (int j = 0; j < m; j++) {
            int   cj = __shfl(c, j);
            float vj = __shfl(v, j);
            acc += vj * x[cj * DFEAT + lane];
        }
    }
    out[wid * DFEAT + lane] = acc + x0[wid * DFEAT + lane] + bias[lane];
}

extern "C" void kernel_launch(void* const* d_in, const int* in_sizes, int n_in,
                              void* d_out, int out_size, void* d_ws, size_t ws_size,
                              hipStream_t stream) {
    const float* x    = (const float*)d_in[0];
    const float* x0   = (const float*)d_in[1];
    const float* ev   = (const float*)d_in[2];
    // d_in[3] = weight: unused (Cayley == identity)
    const float* bias = (const float*)d_in[4];
    const int*   er   = (const int*)d_in[5];
    const int*   ec   = (const int*)d_in[6];
    float* out = (float*)d_out;

    int E = in_sizes[2];
    int N = out_size / DFEAT;

    // workspace layout
    size_t off = 0;
    auto alloc = [&](size_t bytes) {
        size_t o = off;
        off += (bytes + 255) & ~size_t(255);
        return o;
    };
    size_t o_counts   = alloc((size_t)N * 4);
    size_t o_rowstart = alloc(((size_t)N + 1) * 4);
    size_t o_cursor   = alloc((size_t)N * 4);
    size_t o_cols     = alloc((size_t)E * 4);
    size_t o_vals     = alloc((size_t)E * 4);

    if (off <= ws_size) {
        char* ws = (char*)d_ws;
        int*   counts    = (int*)(ws + o_counts);
        int*   row_start = (int*)(ws + o_rowstart);
        int*   cursor    = (int*)(ws + o_cursor);
        int*   cols_s    = (int*)(ws + o_cols);
        float* vals_s    = (float*)(ws + o_vals);

        zero_counts_kernel<<<(N + 255) / 256, 256, 0, stream>>>(counts, N);
        hist_kernel<<<1024, 256, 0, stream>>>(er, counts, E);
        scan_kernel<<<1, SCAN_THREADS, 0, stream>>>(counts, row_start, cursor, N);
        scatter_sort_kernel<<<1024, 256, 0, stream>>>(er, ec, ev, cursor, cols_s, vals_s, E);
        int waves_needed = N;                  // one wave per row
        int blocks = (waves_needed * 64 + 255) / 256;
        spmm_kernel<<<blocks, 256, 0, stream>>>(x, x0, bias, row_start, cols_s, vals_s, out, N);
    } else {
        // fallback: atomic scatter path
        int n4 = out_size / 4;
        init_out_kernel<<<(n4 + 255) / 256, 256, 0, stream>>>(x0, bias, out, n4);
        edge_scatter_kernel<<<8192, 256, 0, stream>>>(x, ev, er, ec, out, E);
    }
}

// Round 3
// 285.260 us; speedup vs baseline: 1.5067x; 1.5067x over previous
//
#include <hip/hip_runtime.h>

// GraphConvolution: out = segment_sum(edge_val * x[edge_col], edge_row) + x_0 + bias
// (Cayley transform in the reference is exactly identity => support == x.)
//
// CSR build (hist -> 3-kernel parallel scan -> counting-sort scatter of packed
// (col,val) pairs), then gather-side SpMM, one wave per row, no output atomics.

#define DFEAT 64
#define SCAN_BLK 1024

// ---------- fallback path (atomic scatter) ----------
__global__ void init_out_kernel(const float* __restrict__ x0,
                                const float* __restrict__ bias,
                                float* __restrict__ out, int n4) {
    int i = blockIdx.x * blockDim.x + threadIdx.x;
    if (i < n4) {
        float4 v = ((const float4*)x0)[i];
        int d = (i * 4) & (DFEAT - 1);
        v.x += bias[d + 0]; v.y += bias[d + 1];
        v.z += bias[d + 2]; v.w += bias[d + 3];
        ((float4*)out)[i] = v;
    }
}

__global__ void edge_scatter_kernel(const float* __restrict__ x,
                                    const float* __restrict__ edge_val,
                                    const int* __restrict__ edge_row,
                                    const int* __restrict__ edge_col,
                                    float* __restrict__ out, int E) {
    int tid = blockIdx.x * blockDim.x + threadIdx.x;
    int wave = tid >> 6, lane = tid & 63;
    int nwaves = (gridDim.x * blockDim.x) >> 6;
    for (int e = wave; e < E; e += nwaves) {
        int row = edge_row[e];
        int col = edge_col[e];
        float val = edge_val[e];
        atomicAdd(&out[row * DFEAT + lane], val * x[col * DFEAT + lane]);
    }
}

// ---------- CSR path ----------
__global__ void zero_counts_kernel(int* __restrict__ counts, int n) {
    int i = blockIdx.x * blockDim.x + threadIdx.x;
    if (i < n) counts[i] = 0;
}

__global__ void hist_kernel(const int* __restrict__ edge_row,
                            int* __restrict__ counts, int E4) {
    // E4 = E/4; edge_row read as int4 (E is 1M here; guard handles tails anyway)
    int i = blockIdx.x * blockDim.x + threadIdx.x;
    int stride = gridDim.x * blockDim.x;
    const int4* er4 = (const int4*)edge_row;
    for (int e = i; e < E4; e += stride) {
        int4 r = er4[e];
        atomicAdd(&counts[r.x], 1);
        atomicAdd(&counts[r.y], 1);
        atomicAdd(&counts[r.z], 1);
        atomicAdd(&counts[r.w], 1);
    }
}

__global__ void hist_tail_kernel(const int* __restrict__ edge_row,
                                 int* __restrict__ counts, int start, int E) {
    int e = start + blockIdx.x * blockDim.x + threadIdx.x;
    if (e < E) atomicAdd(&counts[edge_row[e]], 1);
}

// Stage A: per-block (1024-wide) exclusive scan; local prefix -> row_start,
// block total -> blocksums.
__global__ void scan_local_kernel(const int* __restrict__ counts,
                                  int* __restrict__ row_start,
                                  int* __restrict__ blocksums, int n) {
    __shared__ int sh[SCAN_BLK];
    int t = threadIdx.x;
    int gid = blockIdx.x * SCAN_BLK + t;
    int v = (gid < n) ? counts[gid] : 0;
    sh[t] = v;
    __syncthreads();
    for (int off = 1; off < SCAN_BLK; off <<= 1) {
        int u = (t >= off) ? sh[t - off] : 0;
        __syncthreads();
        sh[t] += u;
        __syncthreads();
    }
    if (gid < n) row_start[gid] = sh[t] - v;   // exclusive
    if (t == SCAN_BLK - 1) blocksums[blockIdx.x] = sh[t];
}

// Stage B: exclusive scan of blocksums (nb <= 1024) in one block.
__global__ void scan_sums_kernel(int* __restrict__ blocksums, int nb) {
    __shared__ int sh[SCAN_BLK];
    int t = threadIdx.x;
    int v = (t < nb) ? blocksums[t] : 0;
    sh[t] = v;
    __syncthreads();
    for (int off = 1; off < SCAN_BLK; off <<= 1) {
        int u = (t >= off) ? sh[t - off] : 0;
        __syncthreads();
        sh[t] += u;
        __syncthreads();
    }
    if (t < nb) blocksums[t] = sh[t] - v;      // exclusive
}

// Stage C: add block offsets; emit cursor copy; one thread writes row_start[n]=E.
__global__ void scan_offset_kernel(int* __restrict__ row_start,
                                   int* __restrict__ cursor,
                                   const int* __restrict__ blocksums,
                                   int n, int E) {
    int gid = blockIdx.x * SCAN_BLK + threadIdx.x;
    if (gid < n) {
        int v = row_start[gid] + blocksums[blockIdx.x];
        row_start[gid] = v;
        cursor[gid] = v;
    }
    if (gid == 0) row_start[n] = E;
}

__global__ void scatter_sort_kernel(const int* __restrict__ edge_row,
                                    const int* __restrict__ edge_col,
                                    const float* __restrict__ edge_val,
                                    int* __restrict__ cursor,
                                    int2* __restrict__ pairs, int E) {
    int i = blockIdx.x * blockDim.x + threadIdx.x;
    int stride = gridDim.x * blockDim.x;
    for (int e = i; e < E; e += stride) {
        int r = edge_row[e];
        int pos = atomicAdd(&cursor[r], 1);
        pairs[pos] = make_int2(edge_col[e], __float_as_int(edge_val[e]));
    }
}

// One 64-lane wave per row; lane d owns feature d. No atomics.
__global__ void spmm_kernel(const float* __restrict__ x,
                            const float* __restrict__ x0,
                            const float* __restrict__ bias,
                            const int* __restrict__ row_start,
                            const int2* __restrict__ pairs,
                            float* __restrict__ out, int n) {
    int wid = (blockIdx.x * blockDim.x + threadIdx.x) >> 6;
    int lane = threadIdx.x & 63;
    if (wid >= n) return;
    int start = row_start[wid];
    int end   = row_start[wid + 1];
    float acc = 0.f;
    for (int s = start; s < end; s += 64) {
        int m = end - s;
        if (m > 64) m = 64;
        int c = 0; float v = 0.f;
        if (lane < m) {
            int2 p = pairs[s + lane];
            c = p.x;
            v = __int_as_float(p.y);
        }
        for (int j = 0; j < m; j++) {
            int   cj = __shfl(c, j);
            float vj = __shfl(v, j);
            acc += vj * x[cj * DFEAT + lane];
        }
    }
    out[wid * DFEAT + lane] = acc + x0[wid * DFEAT + lane] + bias[lane];
}

extern "C" void kernel_launch(void* const* d_in, const int* in_sizes, int n_in,
                              void* d_out, int out_size, void* d_ws, size_t ws_size,
                              hipStream_t stream) {
    const float* x    = (const float*)d_in[0];
    const float* x0   = (const float*)d_in[1];
    const float* ev   = (const float*)d_in[2];
    // d_in[3] = weight: unused (Cayley == identity)
    const float* bias = (const float*)d_in[4];
    const int*   er   = (const int*)d_in[5];
    const int*   ec   = (const int*)d_in[6];
    float* out = (float*)d_out;

    int E = in_sizes[2];
    int N = out_size / DFEAT;
    int nb = (N + SCAN_BLK - 1) / SCAN_BLK;    // scan blocks (64 for N=65536)

    // workspace layout
    size_t off = 0;
    auto alloc = [&](size_t bytes) {
        size_t o = off;
        off += (bytes + 255) & ~size_t(255);
        return o;
    };
    size_t o_counts   = alloc((size_t)N * 4);
    size_t o_rowstart = alloc(((size_t)N + 1) * 4);
    size_t o_cursor   = alloc((size_t)N * 4);
    size_t o_bsums    = alloc((size_t)SCAN_BLK * 4);
    size_t o_pairs    = alloc((size_t)E * 8);

    if (off <= ws_size && nb <= SCAN_BLK) {
        char* ws = (char*)d_ws;
        int*  counts    = (int*)(ws + o_counts);
        int*  row_start = (int*)(ws + o_rowstart);
        int*  cursor    = (int*)(ws + o_cursor);
        int*  bsums     = (int*)(ws + o_bsums);
        int2* pairs     = (int2*)(ws + o_pairs);

        zero_counts_kernel<<<(N + 255) / 256, 256, 0, stream>>>(counts, N);
        int E4 = E / 4;
        if (E4 > 0)
            hist_kernel<<<1024, 256, 0, stream>>>(er, counts, E4);
        if (E4 * 4 < E)
            hist_tail_kernel<<<1, 256, 0, stream>>>(er, counts, E4 * 4, E);
        scan_local_kernel<<<nb, SCAN_BLK, 0, stream>>>(counts, row_start, bsums, N);
        scan_sums_kernel<<<1, SCAN_BLK, 0, stream>>>(bsums, nb);
        scan_offset_kernel<<<nb, SCAN_BLK, 0, stream>>>(row_start, cursor, bsums, N, E);
        scatter_sort_kernel<<<1024, 256, 0, stream>>>(er, ec, ev, cursor, pairs, E);
        int blocks = (N * 64 + 255) / 256;     // one wave per row
        spmm_kernel<<<blocks, 256, 0, stream>>>(x, x0, bias, row_start, pairs, out, N);
    } else {
        // fallback: atomic scatter path
        int n4 = out_size / 4;
        init_out_kernel<<<(n4 + 255) / 256, 256, 0, stream>>>(x0, bias, out, n4);
        edge_scatter_kernel<<<8192, 256, 0, stream>>>(x, ev, er, ec, out, E);
    }
}

// Round 4
// 259.651 us; speedup vs baseline: 1.6553x; 1.0986x over previous
//
#include <hip/hip_runtime.h>

// GraphConvolution: out = segment_sum(edge_val * x[edge_col], edge_row) + x_0 + bias
// (Cayley transform in the reference is exactly identity => support == x.)
//
// Round 4: one-pass fixed-capacity bucket build (no hist/scan/sort).
//   bucket[r*C + pos] = edge_id  (4 B scatter, half the amplified traffic of
//   the 8 B pair scatter), cursor[r] doubles as the row count.
//   Overflow edges (degree > C; ~never for Poisson(16) degrees, C=48/32)
//   are atomically added straight into out, which is pre-initialized to
//   x_0 + bias. SpMM then does wave-per-row gather with no output atomics.

#define DFEAT 64

// out = x_0 + bias  (vectorized float4; D=64 divisible by 4 so no bias wrap)
__global__ void init_out_kernel(const float* __restrict__ x0,
                                const float* __restrict__ bias,
                                float* __restrict__ out, int n4) {
    int i = blockIdx.x * blockDim.x + threadIdx.x;
    if (i < n4) {
        float4 v = ((const float4*)x0)[i];
        int d = (i * 4) & (DFEAT - 1);
        v.x += bias[d + 0]; v.y += bias[d + 1];
        v.z += bias[d + 2]; v.w += bias[d + 3];
        ((float4*)out)[i] = v;
    }
}

// One thread per edge: claim a slot in the row's bucket, store the edge id.
// Overflow (pos >= C): atomically accumulate into out directly (rare path).
__global__ void bucket_scatter_kernel(const int* __restrict__ edge_row,
                                      const int* __restrict__ edge_col,
                                      const float* __restrict__ edge_val,
                                      const float* __restrict__ x,
                                      int* __restrict__ cursor,
                                      int* __restrict__ bucket,
                                      float* __restrict__ out,
                                      int E, int C) {
    int i = blockIdx.x * blockDim.x + threadIdx.x;
    int stride = gridDim.x * blockDim.x;
    for (int e = i; e < E; e += stride) {
        int r = edge_row[e];
        int pos = atomicAdd(&cursor[r], 1);
        if (pos < C) {
            bucket[r * C + pos] = e;
        } else {
            // rare overflow: accumulate this edge directly (out = x0+bias already)
            int c = edge_col[e];
            float v = edge_val[e];
            for (int d = 0; d < DFEAT; d++)
                atomicAdd(&out[r * DFEAT + d], v * x[c * DFEAT + d]);
        }
    }
}

// One 64-lane wave per row; lane d owns feature d. No atomics.
__global__ void spmm_kernel(const float* __restrict__ x,
                            const int* __restrict__ edge_col,
                            const float* __restrict__ edge_val,
                            const int* __restrict__ cursor,
                            const int* __restrict__ bucket,
                            float* __restrict__ out, int n, int C) {
    int wid = (blockIdx.x * blockDim.x + threadIdx.x) >> 6;
    int lane = threadIdx.x & 63;
    if (wid >= n) return;
    int cnt = cursor[wid];
    if (cnt > C) cnt = C;          // overflow edges already folded into out
    int base = wid * C;
    float acc = 0.f;
    for (int s = 0; s < cnt; s += 64) {
        int m = cnt - s;
        if (m > 64) m = 64;
        int c = 0; float v = 0.f;
        if (lane < m) {
            int eid = bucket[base + s + lane];
            c = edge_col[eid];
            v = edge_val[eid];
        }
        for (int j = 0; j < m; j++) {
            int   cj = __shfl(c, j);
            float vj = __shfl(v, j);
            acc += vj * x[cj * DFEAT + lane];
        }
    }
    out[wid * DFEAT + lane] += acc;   // out was pre-set to x0 + bias
}

// ---------- fallback path (round-1 atomic scatter; used only if ws too small) ----------
__global__ void edge_scatter_kernel(const float* __restrict__ x,
                                    const float* __restrict__ edge_val,
                                    const int* __restrict__ edge_row,
                                    const int* __restrict__ edge_col,
                                    float* __restrict__ out, int E) {
    int tid = blockIdx.x * blockDim.x + threadIdx.x;
    int wave = tid >> 6, lane = tid & 63;
    int nwaves = (gridDim.x * blockDim.x) >> 6;
    for (int e = wave; e < E; e += nwaves) {
        int row = edge_row[e];
        int col = edge_col[e];
        float val = edge_val[e];
        atomicAdd(&out[row * DFEAT + lane], val * x[col * DFEAT + lane]);
    }
}

extern "C" void kernel_launch(void* const* d_in, const int* in_sizes, int n_in,
                              void* d_out, int out_size, void* d_ws, size_t ws_size,
                              hipStream_t stream) {
    const float* x    = (const float*)d_in[0];
    const float* x0   = (const float*)d_in[1];
    const float* ev   = (const float*)d_in[2];
    // d_in[3] = weight: unused (Cayley == identity)
    const float* bias = (const float*)d_in[4];
    const int*   er   = (const int*)d_in[5];
    const int*   ec   = (const int*)d_in[6];
    float* out = (float*)d_out;

    int E = in_sizes[2];
    int N = out_size / DFEAT;
    int n4 = out_size / 4;

    // Pick the largest bucket capacity that fits the workspace.
    // Layout: cursor[N] then bucket[N*C], both 256 B aligned.
    size_t cursor_bytes = ((size_t)N * 4 + 255) & ~size_t(255);
    int C = 0;
    for (int cand : {64, 48, 32, 24}) {
        if (cursor_bytes + (size_t)N * cand * 4 <= ws_size) { C = cand; break; }
    }

    // out = x0 + bias first in all paths.
    init_out_kernel<<<(n4 + 255) / 256, 256, 0, stream>>>(x0, bias, out, n4);

    if (C >= 24) {
        char* ws = (char*)d_ws;
        int* cursor = (int*)ws;
        int* bucket = (int*)(ws + cursor_bytes);

        hipMemsetAsync(cursor, 0, (size_t)N * 4, stream);
        bucket_scatter_kernel<<<2048, 256, 0, stream>>>(er, ec, ev, x, cursor,
                                                        bucket, out, E, C);
        int blocks = (N * 64 + 255) / 256;   // one wave per row
        spmm_kernel<<<blocks, 256, 0, stream>>>(x, ec, ev, cursor, bucket, out, N, C);
    } else {
        // workspace too small: atomic-scatter fallback (correct, slower)
        edge_scatter_kernel<<<8192, 256, 0, stream>>>(x, ev, er, ec, out, E);
    }
}